// Round 1
// baseline (588.127 us; speedup 1.0000x reference)
//
#include <hip/hip_runtime.h>
#include <math.h>

// Problem constants (from reference)
#define NPATCH 8192
#define KC     10
#define DIN    1024
#define DH     512
#define DA     256
#define NCLS   4

// phi kernel tiling
#define TM 32    // patches per block
#define BK 64    // K-chunk for layer-1 A staging

// Workspace layout (bytes)
#define OFF_CNT  0                          // int[KC]
#define OFF_IDX  256                        // int[KC*NPATCH]
#define OFF_PSUM (256 + KC*NPATCH*4)        // float[KC*DH]
#define OFF_H    (OFF_PSUM + KC*DH*4)       // float[KC*DH]
#define OFF_S    (OFF_H + KC*DH*4)          // float[KC]

#define FMA8(a, w0, w1, accrow)                                   \
  accrow[0] = fmaf(a, w0.x, accrow[0]);                           \
  accrow[1] = fmaf(a, w0.y, accrow[1]);                           \
  accrow[2] = fmaf(a, w0.z, accrow[2]);                           \
  accrow[3] = fmaf(a, w0.w, accrow[3]);                           \
  accrow[4] = fmaf(a, w1.x, accrow[4]);                           \
  accrow[5] = fmaf(a, w1.y, accrow[5]);                           \
  accrow[6] = fmaf(a, w1.z, accrow[6]);                           \
  accrow[7] = fmaf(a, w1.w, accrow[7]);

// Accumulate acc[8][8] += Ash[rg*8+i][0:KLEN] @ W[0:KLEN][c0:c0+8]
// A reads are wave-uniform (all 64 lanes of a wave share rg) -> LDS broadcast.
template <int LDA, int KLEN>
__device__ __forceinline__ void mm_accum(const float (*Ash)[LDA], int rg,
                                         const float* __restrict__ Wbase,
                                         int c0, float acc[8][8]) {
  for (int kk4 = 0; kk4 < KLEN / 4; ++kk4) {
    float4 av[8];
#pragma unroll
    for (int i = 0; i < 8; ++i)
      av[i] = *(const float4*)&Ash[rg * 8 + i][kk4 * 4];
#pragma unroll
    for (int u = 0; u < 4; ++u) {
      const float* wr = Wbase + (size_t)(kk4 * 4 + u) * DH + c0;
      float4 w0 = *(const float4*)wr;
      float4 w1 = *(const float4*)(wr + 4);
#pragma unroll
      for (int i = 0; i < 8; ++i) {
        float a = (u == 0) ? av[i].x : (u == 1) ? av[i].y : (u == 2) ? av[i].z : av[i].w;
        FMA8(a, w0, w1, acc[i]);
      }
    }
  }
}

__global__ void init_kernel(int* __restrict__ cnt, float* __restrict__ psum) {
  int t = threadIdx.x;
  if (t < KC) cnt[t] = 0;
  for (int i = t; i < KC * DH; i += 256) psum[i] = 0.f;
}

__global__ void bucket_kernel(const int* __restrict__ cid, int* __restrict__ cnt,
                              int* __restrict__ idxlist) {
  int n = blockIdx.x * blockDim.x + threadIdx.x;
  if (n < NPATCH) {
    int k = cid[n];
    int slot = atomicAdd(&cnt[k], 1);
    idxlist[k * NPATCH + slot] = n;
  }
}

// Fused per-cluster 2-layer MLP + masked-sum pool.
// grid = (ceil(NPATCH/TM), KC); blocks beyond cnt[k] exit immediately.
__global__ __launch_bounds__(256) void phi_kernel(
    const float* __restrict__ x, const float* __restrict__ W1,
    const float* __restrict__ b1, const float* __restrict__ W2,
    const float* __restrict__ b2, const int* __restrict__ cnt,
    const int* __restrict__ idxlist, float* __restrict__ psum) {
  const int k = blockIdx.y;
  const int base = blockIdx.x * TM;
  const int cntk = cnt[k];
  if (base >= cntk) return;

  const int tid = threadIdx.x;
  const int cg = tid & 63;   // col group: 64 groups x 8 cols = 512
  const int rg = tid >> 6;   // row group: 4 groups x 8 rows  = 32
  const int c0 = cg * 8;

  __shared__ __align__(16) float a_sh[TM][BK];    // 8 KB
  __shared__ __align__(16) float h1_sh[TM][DH];   // 64 KB
  __shared__ int ridx[TM];

  if (tid < TM) {
    int r = base + tid;
    ridx[tid] = (r < cntk) ? idxlist[k * NPATCH + r] : -1;
  }
  __syncthreads();

  float acc[8][8];
#pragma unroll
  for (int i = 0; i < 8; ++i)
#pragma unroll
    for (int j = 0; j < 8; ++j) acc[i][j] = 0.f;

  const float* W1k = W1 + (size_t)k * DIN * DH;

  // ---- layer 1: h1 = relu(X[32xDIN] @ W1k[DINxDH] + b1) ----
  const int srow = tid >> 3;            // staging: 8 threads per row
  const int scol = (tid & 7) * 8;       // 8 floats each (2x float4)
  for (int ko = 0; ko < DIN; ko += BK) {
    __syncthreads();  // a_sh reuse
    int src = ridx[srow];
    const float* xr = x + (size_t)(src < 0 ? 0 : src) * DIN + ko + scol;
    float4 z = make_float4(0.f, 0.f, 0.f, 0.f);
#pragma unroll
    for (int q = 0; q < 2; ++q) {
      float4 v = (src >= 0) ? *(const float4*)(xr + q * 4) : z;
      *(float4*)&a_sh[srow][scol + q * 4] = v;
    }
    __syncthreads();
    mm_accum<BK, BK>(a_sh, rg, W1k + (size_t)ko * DH, c0, acc);
  }

  // bias + relu -> h1_sh
  {
    const float* b1k = b1 + (size_t)k * DH + c0;
    float4 bv0 = *(const float4*)b1k;
    float4 bv1 = *(const float4*)(b1k + 4);
#pragma unroll
    for (int i = 0; i < 8; ++i) {
      int r = rg * 8 + i;
      h1_sh[r][c0 + 0] = fmaxf(acc[i][0] + bv0.x, 0.f);
      h1_sh[r][c0 + 1] = fmaxf(acc[i][1] + bv0.y, 0.f);
      h1_sh[r][c0 + 2] = fmaxf(acc[i][2] + bv0.z, 0.f);
      h1_sh[r][c0 + 3] = fmaxf(acc[i][3] + bv0.w, 0.f);
      h1_sh[r][c0 + 4] = fmaxf(acc[i][4] + bv1.x, 0.f);
      h1_sh[r][c0 + 5] = fmaxf(acc[i][5] + bv1.y, 0.f);
      h1_sh[r][c0 + 6] = fmaxf(acc[i][6] + bv1.z, 0.f);
      h1_sh[r][c0 + 7] = fmaxf(acc[i][7] + bv1.w, 0.f);
    }
  }
  __syncthreads();

  // ---- layer 2: y = relu(h1[32xDH] @ W2k[DHxDH] + b2) ----
#pragma unroll
  for (int i = 0; i < 8; ++i)
#pragma unroll
    for (int j = 0; j < 8; ++j) acc[i][j] = 0.f;

  const float* W2k = W2 + (size_t)k * DH * DH;
  mm_accum<DH, DH>(h1_sh, rg, W2k, c0, acc);

  // bias + relu, mask out padded rows, reduce over this thread's rows
  {
    const float* b2k = b2 + (size_t)k * DH + c0;
    float4 bv0 = *(const float4*)b2k;
    float4 bv1 = *(const float4*)(b2k + 4);
    float part[8] = {0.f, 0.f, 0.f, 0.f, 0.f, 0.f, 0.f, 0.f};
#pragma unroll
    for (int i = 0; i < 8; ++i) {
      if (ridx[rg * 8 + i] >= 0) {
        part[0] += fmaxf(acc[i][0] + bv0.x, 0.f);
        part[1] += fmaxf(acc[i][1] + bv0.y, 0.f);
        part[2] += fmaxf(acc[i][2] + bv0.z, 0.f);
        part[3] += fmaxf(acc[i][3] + bv0.w, 0.f);
        part[4] += fmaxf(acc[i][4] + bv1.x, 0.f);
        part[5] += fmaxf(acc[i][5] + bv1.y, 0.f);
        part[6] += fmaxf(acc[i][6] + bv1.z, 0.f);
        part[7] += fmaxf(acc[i][7] + bv1.w, 0.f);
      }
    }
#pragma unroll
    for (int j = 0; j < 8; ++j)
      atomicAdd(&psum[k * DH + c0 + j], part[j]);
  }
}

// Per-cluster: pooled mean -> fc+relu -> gated attention score. grid = KC.
__global__ __launch_bounds__(256) void head_kernel(
    const float* __restrict__ psum, const int* __restrict__ cnt,
    const float* __restrict__ fcW, const float* __restrict__ fcb,
    const float* __restrict__ Va, const float* __restrict__ ba,
    const float* __restrict__ Vb, const float* __restrict__ bb_,
    const float* __restrict__ Vc, const float* __restrict__ bc,
    float* __restrict__ hstore, float* __restrict__ sstore) {
  int k = blockIdx.x, tid = threadIdx.x;
  __shared__ float p_sh[DH];
  __shared__ float h_sh[DH];
  __shared__ float red[256];

  int c = cnt[k];
  float inv = (c > 0) ? 1.f / (float)c : 0.f;  // empty cluster -> pooled = 0
  for (int d = tid; d < DH; d += 256) p_sh[d] = psum[k * DH + d] * inv;
  __syncthreads();

#pragma unroll
  for (int jj = 0; jj < 2; ++jj) {
    int j = tid + jj * 256;
    float s = fcb[j];
    for (int d = 0; d < DH; ++d) s = fmaf(p_sh[d], fcW[d * DH + j], s);
    float h = fmaxf(s, 0.f);
    h_sh[j] = h;
    hstore[k * DH + j] = h;
  }
  __syncthreads();

  // gated attention: a = tanh(h@Va+ba), b = sigmoid(h@Vb+bb), s_k = (a*b)@Vc + bc
  {
    int j = tid;  // DA == 256 == blockDim
    float sa = ba[j], sb = bb_[j];
    for (int d = 0; d < DH; ++d) {
      float h = h_sh[d];
      sa = fmaf(h, Va[d * DA + j], sa);
      sb = fmaf(h, Vb[d * DA + j], sb);
    }
    float a = tanhf(sa);
    float b = 1.f / (1.f + expf(-sb));
    red[tid] = a * b * Vc[j];
  }
  __syncthreads();
  for (int s = 128; s > 0; s >>= 1) {
    if (tid < s) red[tid] += red[tid + s];
    __syncthreads();
  }
  if (tid == 0) sstore[k] = red[0] + bc[0];
}

// softmax over K -> h_path -> rho -> classifier -> hazards/S/Y_hat. 1 block.
__global__ __launch_bounds__(256) void tail_kernel(
    const float* __restrict__ hstore, const float* __restrict__ sstore,
    const float* __restrict__ rhoW, const float* __restrict__ rhob,
    const float* __restrict__ clsW, const float* __restrict__ clsb,
    float* __restrict__ out) {
  int tid = threadIdx.x;
  __shared__ float hp_sh[DH];
  __shared__ float h2_sh[DA];
  __shared__ float lg[NCLS];

  float sv[KC];
  float m = -1e30f;
#pragma unroll
  for (int k = 0; k < KC; ++k) {
    sv[k] = sstore[k];
    m = fmaxf(m, sv[k]);
  }
  float Z = 0.f;
#pragma unroll
  for (int k = 0; k < KC; ++k) {
    sv[k] = expf(sv[k] - m);
    Z += sv[k];
  }
  float invZ = 1.f / Z;

#pragma unroll
  for (int jj = 0; jj < 2; ++jj) {
    int d = tid + jj * 256;
    float s = 0.f;
#pragma unroll
    for (int k = 0; k < KC; ++k) s = fmaf(sv[k] * invZ, hstore[k * DH + d], s);
    hp_sh[d] = s;
  }
  __syncthreads();

  if (tid < DA) {
    float s = rhob[tid];
    for (int d = 0; d < DH; ++d) s = fmaf(hp_sh[d], rhoW[d * DA + tid], s);
    h2_sh[tid] = fmaxf(s, 0.f);
  }
  __syncthreads();

  if (tid < NCLS) {
    float s = clsb[tid];
    for (int d = 0; d < DA; ++d) s = fmaf(h2_sh[d], clsW[d * NCLS + tid], s);
    lg[tid] = s;
  }
  __syncthreads();

  if (tid == 0) {
    float hz[NCLS];
    int best = 0;
#pragma unroll
    for (int c = 0; c < NCLS; ++c) {
      hz[c] = 1.f / (1.f + expf(-lg[c]));
      if (lg[c] > lg[best]) best = c;  // strict > keeps first max (argmax semantics)
    }
    float S = 1.f;
#pragma unroll
    for (int c = 0; c < NCLS; ++c) out[c] = hz[c];
#pragma unroll
    for (int c = 0; c < NCLS; ++c) {
      S *= (1.f - hz[c]);
      out[NCLS + c] = S;
    }
    out[2 * NCLS] = (float)best;  // Y_hat
  }
}

extern "C" void kernel_launch(void* const* d_in, const int* in_sizes, int n_in,
                              void* d_out, int out_size, void* d_ws,
                              size_t ws_size, hipStream_t stream) {
  const float* x    = (const float*)d_in[0];
  const int*   cid  = (const int*)d_in[1];
  const float* W1   = (const float*)d_in[2];
  const float* b1   = (const float*)d_in[3];
  const float* W2   = (const float*)d_in[4];
  const float* b2   = (const float*)d_in[5];
  const float* fcW  = (const float*)d_in[6];
  const float* fcb  = (const float*)d_in[7];
  const float* Va   = (const float*)d_in[8];
  const float* ba   = (const float*)d_in[9];
  const float* Vb   = (const float*)d_in[10];
  const float* bb_  = (const float*)d_in[11];
  const float* Vc   = (const float*)d_in[12];
  const float* bc   = (const float*)d_in[13];
  const float* rhoW = (const float*)d_in[14];
  const float* rhob = (const float*)d_in[15];
  const float* clsW = (const float*)d_in[16];
  const float* clsb = (const float*)d_in[17];
  float* out = (float*)d_out;

  char* ws = (char*)d_ws;
  int*   cnt     = (int*)(ws + OFF_CNT);
  int*   idxlist = (int*)(ws + OFF_IDX);
  float* psum    = (float*)(ws + OFF_PSUM);
  float* hstore  = (float*)(ws + OFF_H);
  float* sstore  = (float*)(ws + OFF_S);

  init_kernel<<<1, 256, 0, stream>>>(cnt, psum);
  bucket_kernel<<<NPATCH / 256, 256, 0, stream>>>(cid, cnt, idxlist);
  phi_kernel<<<dim3((NPATCH + TM - 1) / TM, KC), 256, 0, stream>>>(
      x, W1, b1, W2, b2, cnt, idxlist, psum);
  head_kernel<<<KC, 256, 0, stream>>>(psum, cnt, fcW, fcb, Va, ba, Vb, bb_, Vc,
                                      bc, hstore, sstore);
  tail_kernel<<<1, 256, 0, stream>>>(hstore, sstore, rhoW, rhob, clsW, clsb, out);
}

// Round 2
// 279.414 us; speedup vs baseline: 2.1049x; 2.1049x over previous
//
#include <hip/hip_runtime.h>
#include <math.h>

// Problem constants (from reference)
#define NPATCH 8192
#define KC     10
#define DIN    1024
#define DH     512
#define DA     256
#define NCLS   4

#define TM 32    // patches per phi block

typedef unsigned short u16;
typedef short bf16x8 __attribute__((ext_vector_type(8)));   // 8 bf16 = 4 VGPRs
typedef float f32x4  __attribute__((ext_vector_type(4)));

// Workspace layout (bytes)
#define OFF_CNT   0                         // int[KC] (padded)
#define OFF_IDX   256                       // int[KC*NPATCH] = 327680
#define OFF_PSUM  327936                    // float[KC*DH] = 20480
#define OFF_H     348416                    // float[KC*DH] = 20480
#define OFF_S     368896                    // float[KC] (padded 64)
#define OFF_W1P   368960                    // u16[KC*DIN*DH] = 10485760
#define OFF_W2P   10854720                  // u16[KC*DH*DH]  = 5242880
// total ~16.1 MB

__device__ __forceinline__ u16 f2bf(float f) {
  union { float f; unsigned u; } v; v.f = f;
  unsigned r = (v.u + 0x7fffu + ((v.u >> 16) & 1u)) >> 16;  // RNE
  return (u16)r;
}

struct __align__(8) U16x4 { u16 x, y, z, w; };

__global__ void init_kernel(int* __restrict__ cnt, float* __restrict__ psum) {
  int t = threadIdx.x;
  if (t < KC) cnt[t] = 0;
  for (int i = t; i < KC * DH; i += 256) psum[i] = 0.f;
}

// LDS-histogram bucketing: 10 global atomics per block instead of 256.
__global__ __launch_bounds__(256) void bucket_kernel(const int* __restrict__ cid,
                                                     int* __restrict__ cnt,
                                                     int* __restrict__ idxlist) {
  __shared__ int lcnt[KC], lbase[KC];
  int t = threadIdx.x;
  if (t < KC) lcnt[t] = 0;
  __syncthreads();
  int n = blockIdx.x * 256 + t;          // NPATCH % 256 == 0
  int k = cid[n];
  int myoff = atomicAdd(&lcnt[k], 1);
  __syncthreads();
  if (t < KC) lbase[t] = atomicAdd(&cnt[t], lcnt[t]);
  __syncthreads();
  idxlist[k * NPATCH + lbase[k] + myoff] = n;
}

// Pack W1/W2 fp32 [k][kk][n] -> bf16 MFMA-B panels [k][kb][n][ki], kb=kk/32, ki=kk%32.
// One 32x32 tile per block via LDS transpose; reads and writes both coalesced.
#define W1_TILES (KC * (DIN / 32) * (DH / 32))  // 5120
#define W2_TILES (KC * (DH / 32) * (DH / 32))   // 2560
__global__ __launch_bounds__(256) void pack_kernel(const float* __restrict__ W1,
                                                   const float* __restrict__ W2,
                                                   u16* __restrict__ W1p,
                                                   u16* __restrict__ W2p) {
  __shared__ u16 tile[32][33];
  int b = blockIdx.x;
  const float* src;
  u16* dst;
  if (b < W1_TILES) {
    int k = b / 512, rem = b % 512;
    int kb = rem / 16, n0 = (rem % 16) * 32;
    src = W1 + (size_t)k * DIN * DH + (size_t)kb * 32 * DH + n0;
    dst = W1p + (((size_t)(k * 32 + kb) * 512 + n0) * 32);
  } else {
    int bb = b - W1_TILES;
    int k = bb / 256, rem = bb % 256;
    int kb = rem / 16, n0 = (rem % 16) * 32;
    src = W2 + (size_t)k * DH * DH + (size_t)kb * 32 * DH + n0;
    dst = W2p + (((size_t)(k * 16 + kb) * 512 + n0) * 32);
  }
  int t = threadIdx.x;
#pragma unroll
  for (int i = 0; i < 4; ++i) {
    int e = t + i * 256;
    int ki = e >> 5, n = e & 31;
    tile[ki][n] = f2bf(src[(size_t)ki * DH + n]);
  }
  __syncthreads();
#pragma unroll
  for (int i = 0; i < 4; ++i) {
    int e = t + i * 256;
    int n = e >> 5, ki = e & 31;
    dst[(size_t)n * 32 + ki] = tile[ki][n];
  }
}

// Fused per-cluster 2-layer MLP (bf16 MFMA) + masked-sum pool.
// Block = 256 thr = 4 waves. M-tile 32 rows; wave w owns cols [w*128, w*128+128).
// MFMA 16x16x32 layouts (m89-verified): A[m=lane&15][k=quad*8+j],
// B[n=lane&15][k=quad*8+j], C/D col=lane&15 row=quad*4+reg.
__global__ __launch_bounds__(256) void phi_mfma(
    const float* __restrict__ x, const u16* __restrict__ W1p,
    const float* __restrict__ b1, const u16* __restrict__ W2p,
    const float* __restrict__ b2, const int* __restrict__ cnt,
    const int* __restrict__ idxlist, float* __restrict__ psum) {
  const int k = blockIdx.y;
  const int base = blockIdx.x * TM;
  const int cntk = cnt[k];
  if (base >= cntk) return;

  const int tid = threadIdx.x;
  const int w = tid >> 6, lane = tid & 63;
  const int quad = lane >> 4, l16 = lane & 15;

  __shared__ u16 A_sh[TM][512];   // 32 KB — layer-1 A half-panel (bf16)
  __shared__ u16 h1_sh[TM][512];  // 32 KB — layer-2 A panel (bf16)
  __shared__ int ridx[TM];

  if (tid < TM) {
    int r = base + tid;
    ridx[tid] = (r < cntk) ? idxlist[k * NPATCH + r] : -1;
  }
  __syncthreads();

  const f32x4 zero4 = {0.f, 0.f, 0.f, 0.f};
  f32x4 acc[2][8];
#pragma unroll
  for (int mt = 0; mt < 2; ++mt)
#pragma unroll
    for (int nt = 0; nt < 8; ++nt) acc[mt][nt] = zero4;

  const int srow = tid >> 3;          // staging: 8 threads per row
  const int scol0 = (tid & 7) * 4;
  const long asrc = ridx[srow];

  // ---- layer 1: h1 = relu(X @ W1k + b1), K=1024 in two 512-halves ----
  for (int kh = 0; kh < 2; ++kh) {
    __syncthreads();  // A_sh reuse between halves
    if (asrc >= 0) {
      const float* xr = x + asrc * DIN + kh * 512;
#pragma unroll
      for (int c = 0; c < 16; ++c) {
        int col = scol0 + c * 32;
        float4 v = *(const float4*)(xr + col);
        U16x4 o = {f2bf(v.x), f2bf(v.y), f2bf(v.z), f2bf(v.w)};
        *(U16x4*)&A_sh[srow][col] = o;
      }
    } else {
      U16x4 o = {0, 0, 0, 0};
#pragma unroll
      for (int c = 0; c < 16; ++c) *(U16x4*)&A_sh[srow][scol0 + c * 32] = o;
    }
    __syncthreads();

    for (int ks = 0; ks < 16; ++ks) {
      bf16x8 af0 = *(const bf16x8*)&A_sh[l16][ks * 32 + quad * 8];
      bf16x8 af1 = *(const bf16x8*)&A_sh[16 + l16][ks * 32 + quad * 8];
      const u16* wp = W1p + (((size_t)(k * 32 + kh * 16 + ks) * 512) +
                             (w * 128 + l16)) * 32 + quad * 8;
#pragma unroll
      for (int nt = 0; nt < 8; ++nt) {
        bf16x8 bf = *(const bf16x8*)(wp + (size_t)nt * 16 * 32);
        acc[0][nt] = __builtin_amdgcn_mfma_f32_16x16x32_bf16(af0, bf, acc[0][nt], 0, 0, 0);
        acc[1][nt] = __builtin_amdgcn_mfma_f32_16x16x32_bf16(af1, bf, acc[1][nt], 0, 0, 0);
      }
    }
  }

  // epilogue 1: bias + relu -> h1_sh (bf16)
#pragma unroll
  for (int mt = 0; mt < 2; ++mt)
#pragma unroll
    for (int nt = 0; nt < 8; ++nt) {
      int col = w * 128 + nt * 16 + l16;
      float bias = b1[k * DH + col];
#pragma unroll
      for (int r = 0; r < 4; ++r) {
        int row = mt * 16 + quad * 4 + r;
        h1_sh[row][col] = f2bf(fmaxf(acc[mt][nt][r] + bias, 0.f));
      }
    }
  __syncthreads();

  // ---- layer 2: y = relu(h1 @ W2k + b2), K=512 ----
#pragma unroll
  for (int mt = 0; mt < 2; ++mt)
#pragma unroll
    for (int nt = 0; nt < 8; ++nt) acc[mt][nt] = zero4;

  for (int ks = 0; ks < 16; ++ks) {
    bf16x8 af0 = *(const bf16x8*)&h1_sh[l16][ks * 32 + quad * 8];
    bf16x8 af1 = *(const bf16x8*)&h1_sh[16 + l16][ks * 32 + quad * 8];
    const u16* wp = W2p + (((size_t)(k * 16 + ks) * 512) +
                           (w * 128 + l16)) * 32 + quad * 8;
#pragma unroll
    for (int nt = 0; nt < 8; ++nt) {
      bf16x8 bf = *(const bf16x8*)(wp + (size_t)nt * 16 * 32);
      acc[0][nt] = __builtin_amdgcn_mfma_f32_16x16x32_bf16(af0, bf, acc[0][nt], 0, 0, 0);
      acc[1][nt] = __builtin_amdgcn_mfma_f32_16x16x32_bf16(af1, bf, acc[1][nt], 0, 0, 0);
    }
  }

  // epilogue 2: bias + relu, mask padded rows, column-sum, atomic into psum
  float vmask[2][4];
#pragma unroll
  for (int mt = 0; mt < 2; ++mt)
#pragma unroll
    for (int r = 0; r < 4; ++r)
      vmask[mt][r] = (ridx[mt * 16 + quad * 4 + r] >= 0) ? 1.f : 0.f;

  float part[8];
#pragma unroll
  for (int nt = 0; nt < 8; ++nt) {
    int col = w * 128 + nt * 16 + l16;
    float bias = b2[k * DH + col];
    float s = 0.f;
#pragma unroll
    for (int mt = 0; mt < 2; ++mt)
#pragma unroll
      for (int r = 0; r < 4; ++r)
        s += vmask[mt][r] * fmaxf(acc[mt][nt][r] + bias, 0.f);
    s += __shfl_xor(s, 16, 64);
    s += __shfl_xor(s, 32, 64);
    part[nt] = s;
  }
  if (quad == 0) {
#pragma unroll
    for (int nt = 0; nt < 8; ++nt)
      atomicAdd(&psum[k * DH + w * 128 + nt * 16 + l16], part[nt]);
  }
}

// fc: h = relu(pooled @ fcW + fcb). grid (KC, 2); one output per thread.
__global__ __launch_bounds__(256) void fc_kernel(
    const float* __restrict__ psum, const int* __restrict__ cnt,
    const float* __restrict__ fcW, const float* __restrict__ fcb,
    float* __restrict__ hstore) {
  int k = blockIdx.x, half = blockIdx.y, tid = threadIdx.x;
  __shared__ float p_sh[DH];
  int c = cnt[k];
  float inv = (c > 0) ? 1.f / (float)c : 0.f;
  for (int d = tid; d < DH; d += 256) p_sh[d] = psum[k * DH + d] * inv;
  __syncthreads();
  int j = half * 256 + tid;
  float s0 = 0.f, s1 = 0.f, s2 = 0.f, s3 = 0.f;
  for (int d = 0; d < DH; d += 4) {
    s0 = fmaf(p_sh[d + 0], fcW[(d + 0) * DH + j], s0);
    s1 = fmaf(p_sh[d + 1], fcW[(d + 1) * DH + j], s1);
    s2 = fmaf(p_sh[d + 2], fcW[(d + 2) * DH + j], s2);
    s3 = fmaf(p_sh[d + 3], fcW[(d + 3) * DH + j], s3);
  }
  hstore[k * DH + j] = fmaxf((s0 + s1) + (s2 + s3) + fcb[j], 0.f);
}

// gated attention score per cluster. grid KC.
__global__ __launch_bounds__(256) void attn_kernel(
    const float* __restrict__ hstore, const float* __restrict__ Va,
    const float* __restrict__ ba, const float* __restrict__ Vb,
    const float* __restrict__ bb_, const float* __restrict__ Vc,
    const float* __restrict__ bc, float* __restrict__ sstore) {
  int k = blockIdx.x, tid = threadIdx.x;
  __shared__ float h_sh[DH];
  __shared__ float red[256];
  for (int d = tid; d < DH; d += 256) h_sh[d] = hstore[k * DH + d];
  __syncthreads();
  float sa0 = 0.f, sa1 = 0.f, sb0 = 0.f, sb1 = 0.f;
  for (int d = 0; d < DH; d += 2) {
    float h0 = h_sh[d], h1 = h_sh[d + 1];
    sa0 = fmaf(h0, Va[(d + 0) * DA + tid], sa0);
    sa1 = fmaf(h1, Va[(d + 1) * DA + tid], sa1);
    sb0 = fmaf(h0, Vb[(d + 0) * DA + tid], sb0);
    sb1 = fmaf(h1, Vb[(d + 1) * DA + tid], sb1);
  }
  float a = tanhf(sa0 + sa1 + ba[tid]);
  float b = 1.f / (1.f + expf(-(sb0 + sb1 + bb_[tid])));
  red[tid] = a * b * Vc[tid];
  __syncthreads();
  for (int s = 128; s > 0; s >>= 1) {
    if (tid < s) red[tid] += red[tid + s];
    __syncthreads();
  }
  if (tid == 0) sstore[k] = red[0] + bc[0];
}

// softmax over K -> h_path -> rho -> classifier -> hazards/S/Y_hat. 1 block.
__global__ __launch_bounds__(256) void tail_kernel(
    const float* __restrict__ hstore, const float* __restrict__ sstore,
    const float* __restrict__ rhoW, const float* __restrict__ rhob,
    const float* __restrict__ clsW, const float* __restrict__ clsb,
    float* __restrict__ out) {
  int tid = threadIdx.x;
  __shared__ float hp_sh[DH];
  __shared__ float h2_sh[DA];
  __shared__ float lg[NCLS];

  float sv[KC];
  float m = -1e30f;
#pragma unroll
  for (int k = 0; k < KC; ++k) {
    sv[k] = sstore[k];
    m = fmaxf(m, sv[k]);
  }
  float Z = 0.f;
#pragma unroll
  for (int k = 0; k < KC; ++k) {
    sv[k] = expf(sv[k] - m);
    Z += sv[k];
  }
  float invZ = 1.f / Z;

#pragma unroll
  for (int jj = 0; jj < 2; ++jj) {
    int d = tid + jj * 256;
    float s = 0.f;
#pragma unroll
    for (int k = 0; k < KC; ++k) s = fmaf(sv[k] * invZ, hstore[k * DH + d], s);
    hp_sh[d] = s;
  }
  __syncthreads();

  if (tid < DA) {
    float s0 = 0.f, s1 = 0.f, s2 = 0.f, s3 = 0.f;
    for (int d = 0; d < DH; d += 4) {
      s0 = fmaf(hp_sh[d + 0], rhoW[(d + 0) * DA + tid], s0);
      s1 = fmaf(hp_sh[d + 1], rhoW[(d + 1) * DA + tid], s1);
      s2 = fmaf(hp_sh[d + 2], rhoW[(d + 2) * DA + tid], s2);
      s3 = fmaf(hp_sh[d + 3], rhoW[(d + 3) * DA + tid], s3);
    }
    h2_sh[tid] = fmaxf((s0 + s1) + (s2 + s3) + rhob[tid], 0.f);
  }
  __syncthreads();

  if (tid < NCLS) {
    float s = clsb[tid];
    for (int d = 0; d < DA; ++d) s = fmaf(h2_sh[d], clsW[d * NCLS + tid], s);
    lg[tid] = s;
  }
  __syncthreads();

  if (tid == 0) {
    float hz[NCLS];
    int best = 0;
#pragma unroll
    for (int c = 0; c < NCLS; ++c) {
      hz[c] = 1.f / (1.f + expf(-lg[c]));
      if (lg[c] > lg[best]) best = c;
    }
    float S = 1.f;
#pragma unroll
    for (int c = 0; c < NCLS; ++c) out[c] = hz[c];
#pragma unroll
    for (int c = 0; c < NCLS; ++c) {
      S *= (1.f - hz[c]);
      out[NCLS + c] = S;
    }
    out[2 * NCLS] = (float)best;
  }
}

extern "C" void kernel_launch(void* const* d_in, const int* in_sizes, int n_in,
                              void* d_out, int out_size, void* d_ws,
                              size_t ws_size, hipStream_t stream) {
  const float* x    = (const float*)d_in[0];
  const int*   cid  = (const int*)d_in[1];
  const float* W1   = (const float*)d_in[2];
  const float* b1   = (const float*)d_in[3];
  const float* W2   = (const float*)d_in[4];
  const float* b2   = (const float*)d_in[5];
  const float* fcW  = (const float*)d_in[6];
  const float* fcb  = (const float*)d_in[7];
  const float* Va   = (const float*)d_in[8];
  const float* ba   = (const float*)d_in[9];
  const float* Vb   = (const float*)d_in[10];
  const float* bb_  = (const float*)d_in[11];
  const float* Vc   = (const float*)d_in[12];
  const float* bc   = (const float*)d_in[13];
  const float* rhoW = (const float*)d_in[14];
  const float* rhob = (const float*)d_in[15];
  const float* clsW = (const float*)d_in[16];
  const float* clsb = (const float*)d_in[17];
  float* out = (float*)d_out;

  char* ws = (char*)d_ws;
  int*   cnt     = (int*)(ws + OFF_CNT);
  int*   idxlist = (int*)(ws + OFF_IDX);
  float* psum    = (float*)(ws + OFF_PSUM);
  float* hstore  = (float*)(ws + OFF_H);
  float* sstore  = (float*)(ws + OFF_S);
  u16*   W1p     = (u16*)(ws + OFF_W1P);
  u16*   W2p     = (u16*)(ws + OFF_W2P);

  init_kernel<<<1, 256, 0, stream>>>(cnt, psum);
  bucket_kernel<<<NPATCH / 256, 256, 0, stream>>>(cid, cnt, idxlist);
  pack_kernel<<<W1_TILES + W2_TILES, 256, 0, stream>>>(W1, W2, W1p, W2p);
  phi_mfma<<<dim3(NPATCH / TM, KC), 256, 0, stream>>>(x, W1p, b1, W2p, b2, cnt,
                                                      idxlist, psum);
  fc_kernel<<<dim3(KC, 2), 256, 0, stream>>>(psum, cnt, fcW, fcb, hstore);
  attn_kernel<<<KC, 256, 0, stream>>>(hstore, Va, ba, Vb, bb_, Vc, bc, sstore);
  tail_kernel<<<1, 256, 0, stream>>>(hstore, sstore, rhoW, rhob, clsW, clsb, out);
}

// Round 4
// 270.270 us; speedup vs baseline: 2.1761x; 1.0338x over previous
//
#include <hip/hip_runtime.h>
#include <math.h>

// Problem constants (from reference)
#define NPATCH 8192
#define KC     10
#define DIN    1024
#define DH     512
#define DA     256
#define NCLS   4

#define TM  32    // patches per phi block
#define LDA 520   // padded LDS row stride (u16): 1040 B -> b128 frag reads hit all 32 banks

typedef unsigned short u16;
typedef short bf16x8 __attribute__((ext_vector_type(8)));   // 8 bf16 = 4 VGPRs
typedef float f32x4  __attribute__((ext_vector_type(4)));

// Workspace layout (bytes)
#define OFF_CNT   0                  // int[KC] (64B)
#define OFF_IDX   64                 // int[KC*NPATCH]
#define OFF_PSUM  327744             // float[KC*DH]
#define OFF_H     348224             // float[KC*DH]
#define OFF_S     368704             // float[KC] (64B)
#define OFF_W1P   368768             // u16[KC*DIN*DH]
#define OFF_W2P   10854528           // u16[KC*DH*DH]
#define OFF_XB    16097408           // u16[NPATCH*DIN]
#define OFF_H1    32874624           // u16[NPATCH*DH]
// total ~41.3 MB

__device__ __forceinline__ u16 f2bf(float f) {
  union { float f; unsigned u; } v; v.f = f;
  unsigned r = (v.u + 0x7fffu + ((v.u >> 16) & 1u)) >> 16;  // RNE
  return (u16)r;
}

struct __align__(8) U16x4 { u16 x, y, z, w; };

// Async global->LDS DMA, 16B/lane; LDS dest = wave-uniform base + lane*16.
__device__ __forceinline__ void async16(const void* gp, void* lp) {
  __builtin_amdgcn_global_load_lds(
      (const __attribute__((address_space(1))) void*)gp,
      (__attribute__((address_space(3))) void*)lp, 16, 0, 0);
}

#define W1_TILES (KC * (DIN / 32) * (DH / 32))  // 5120
#define W2_TILES (KC * (DH / 32) * (DH / 32))   // 2560
#define NB_BUCKET 32
#define NB_XB     2048
#define NB_PREP   (NB_BUCKET + W1_TILES + W2_TILES + NB_XB)  // 9760

// Fused prep: bucket + zero psum/sstore (blocks 0..31), pack W1/W2 -> bf16
// MFMA-B panels [k][kb][n][ki], pack x -> bf16 row-major.
__global__ __launch_bounds__(256) void prep_kernel(
    const int* __restrict__ cid, int* __restrict__ cnt,
    int* __restrict__ idxlist, const float* __restrict__ W1,
    const float* __restrict__ W2, u16* __restrict__ W1p,
    u16* __restrict__ W2p, const float* __restrict__ x,
    u16* __restrict__ xb, float* __restrict__ psum,
    float* __restrict__ sstore) {
  int b = blockIdx.x, t = threadIdx.x;
  if (b < NB_BUCKET) {
    int g = b * 256 + t;
    if (g < KC * DH) psum[g] = 0.f;
    if (g < KC) sstore[g] = 0.f;
    __shared__ int lcnt[KC], lbase[KC];
    if (t < KC) lcnt[t] = 0;
    __syncthreads();
    int n = b * 256 + t;                 // NPATCH == 32*256
    int k = cid[n];
    int myoff = atomicAdd(&lcnt[k], 1);
    __syncthreads();
    if (t < KC) lbase[t] = atomicAdd(&cnt[t], lcnt[t]);
    __syncthreads();
    idxlist[k * NPATCH + lbase[k] + myoff] = n;
  } else if (b < NB_BUCKET + W1_TILES + W2_TILES) {
    __shared__ u16 tile[32][33];
    int bb = b - NB_BUCKET;
    const float* src;
    u16* dst;
    if (bb < W1_TILES) {
      int k = bb / 512, rem = bb % 512;
      int kb = rem / 16, n0 = (rem % 16) * 32;
      src = W1 + (size_t)k * DIN * DH + (size_t)kb * 32 * DH + n0;
      dst = W1p + (((size_t)(k * 32 + kb) * 512 + n0) * 32);
    } else {
      int b2 = bb - W1_TILES;
      int k = b2 / 256, rem = b2 % 256;
      int kb = rem / 16, n0 = (rem % 16) * 32;
      src = W2 + (size_t)k * DH * DH + (size_t)kb * 32 * DH + n0;
      dst = W2p + (((size_t)(k * 16 + kb) * 512 + n0) * 32);
    }
#pragma unroll
    for (int i = 0; i < 4; ++i) {
      int e = t + i * 256;
      int ki = e >> 5, n = e & 31;
      tile[ki][n] = f2bf(src[(size_t)ki * DH + n]);
    }
    __syncthreads();
#pragma unroll
    for (int i = 0; i < 4; ++i) {
      int e = t + i * 256;
      int n = e >> 5, ki = e & 31;
      dst[(size_t)n * 32 + ki] = tile[ki][n];
    }
  } else {
    int cb = b - (NB_BUCKET + W1_TILES + W2_TILES);
    size_t basei = (size_t)cb * 4096;
#pragma unroll
    for (int i = 0; i < 4; ++i) {
      size_t off = basei + (size_t)i * 1024 + (size_t)t * 4;
      float4 v = *(const float4*)(x + off);
      U16x4 o = {f2bf(v.x), f2bf(v.y), f2bf(v.z), f2bf(v.w)};
      *(U16x4*)(xb + off) = o;
    }
  }
}

// Layer 1: h1 = relu(x @ W1[k] + b1[k]) for this cluster's patches, bf16 out.
// grid (64, KC, 2): 32-patch chunk, cluster, N-half. 4 waves; wave w owns
// 64 cols of its half. MFMA 16x16x32 (m89 layouts).
__global__ __launch_bounds__(256) void phi1_kernel(
    const u16* __restrict__ xb, const u16* __restrict__ W1p,
    const float* __restrict__ b1, const int* __restrict__ cnt,
    const int* __restrict__ idxlist, u16* __restrict__ h1) {
  const int k = blockIdx.y;
  const int base = blockIdx.x * TM;
  const int nh = blockIdx.z;
  const int cntk = cnt[k];
  if (base >= cntk) return;

  const int tid = threadIdx.x;
  const int w = tid >> 6, lane = tid & 63;
  const int quad = lane >> 4, l16 = lane & 15;

  __shared__ __align__(16) u16 A_sh[TM][LDA];  // 33.3 KB
  __shared__ int ridx[TM];
  if (tid < TM) {
    int r = base + tid;
    ridx[tid] = (r < cntk) ? idxlist[k * NPATCH + r] : -1;
  }
  __syncthreads();

  const f32x4 zero4 = {0.f, 0.f, 0.f, 0.f};
  f32x4 acc[2][4];
#pragma unroll
  for (int mt = 0; mt < 2; ++mt)
#pragma unroll
    for (int nt = 0; nt < 4; ++nt) acc[mt][nt] = zero4;

  for (int kh = 0; kh < 2; ++kh) {
    if (kh) __syncthreads();
    // stage 8 rows per wave via DMA (1 KB row-half each), zero-fill padded
    for (int rr = 0; rr < 8; ++rr) {
      int r = w * 8 + rr;
      int src = ridx[r];
      if (src >= 0) {
        async16(xb + (size_t)src * DIN + kh * 512 + lane * 8, &A_sh[r][0]);
      } else {
        bf16x8 z = {0, 0, 0, 0, 0, 0, 0, 0};
        *(bf16x8*)&A_sh[r][lane * 8] = z;
      }
    }
    __syncthreads();
    for (int ks = 0; ks < 16; ++ks) {
      bf16x8 af0 = *(const bf16x8*)&A_sh[l16][ks * 32 + quad * 8];
      bf16x8 af1 = *(const bf16x8*)&A_sh[16 + l16][ks * 32 + quad * 8];
      const u16* wp = W1p + ((size_t)(k * 32 + kh * 16 + ks) * 512 +
                             (nh * 256 + w * 64 + l16)) * 32 + quad * 8;
#pragma unroll
      for (int nt = 0; nt < 4; ++nt) {
        bf16x8 bf = *(const bf16x8*)(wp + (size_t)nt * 16 * 32);
        acc[0][nt] = __builtin_amdgcn_mfma_f32_16x16x32_bf16(af0, bf, acc[0][nt], 0, 0, 0);
        acc[1][nt] = __builtin_amdgcn_mfma_f32_16x16x32_bf16(af1, bf, acc[1][nt], 0, 0, 0);
      }
    }
  }

  // epilogue: bias+relu -> bf16 via LDS transpose -> coalesced h1 writes
  __syncthreads();
#pragma unroll
  for (int mt = 0; mt < 2; ++mt)
#pragma unroll
    for (int nt = 0; nt < 4; ++nt) {
      int c = w * 64 + nt * 16 + l16;
      float bias = b1[k * DH + nh * 256 + c];
#pragma unroll
      for (int r = 0; r < 4; ++r) {
        int row = mt * 16 + quad * 4 + r;
        A_sh[row][c] = f2bf(fmaxf(acc[mt][nt][r] + bias, 0.f));
      }
    }
  __syncthreads();
  {
    int row = tid >> 3, part = tid & 7;
    int n = ridx[row];
    if (n >= 0) {
      u16* dst = h1 + (size_t)n * DH + nh * 256 + part * 32;
#pragma unroll
      for (int j = 0; j < 4; ++j)
        *(bf16x8*)(dst + j * 8) = *(const bf16x8*)&A_sh[row][part * 32 + j * 8];
    }
  }
}

// Layer 2 + masked mean-pool numerator: psum[k] += relu(h1 @ W2[k] + b2[k]).
__global__ __launch_bounds__(256) void phi2_kernel(
    const u16* __restrict__ h1, const u16* __restrict__ W2p,
    const float* __restrict__ b2, const int* __restrict__ cnt,
    const int* __restrict__ idxlist, float* __restrict__ psum) {
  const int k = blockIdx.y;
  const int base = blockIdx.x * TM;
  const int nh = blockIdx.z;
  const int cntk = cnt[k];
  if (base >= cntk) return;

  const int tid = threadIdx.x;
  const int w = tid >> 6, lane = tid & 63;
  const int quad = lane >> 4, l16 = lane & 15;

  __shared__ __align__(16) u16 H_sh[TM][LDA];
  __shared__ int ridx[TM];
  if (tid < TM) {
    int r = base + tid;
    ridx[tid] = (r < cntk) ? idxlist[k * NPATCH + r] : -1;
  }
  __syncthreads();

  for (int rr = 0; rr < 8; ++rr) {
    int r = w * 8 + rr;
    int src = ridx[r];
    if (src >= 0) {
      async16(h1 + (size_t)src * DH + lane * 8, &H_sh[r][0]);
    } else {
      bf16x8 z = {0, 0, 0, 0, 0, 0, 0, 0};
      *(bf16x8*)&H_sh[r][lane * 8] = z;
    }
  }
  __syncthreads();

  const f32x4 zero4 = {0.f, 0.f, 0.f, 0.f};
  f32x4 acc[2][4];
#pragma unroll
  for (int mt = 0; mt < 2; ++mt)
#pragma unroll
    for (int nt = 0; nt < 4; ++nt) acc[mt][nt] = zero4;

  for (int ks = 0; ks < 16; ++ks) {
    bf16x8 af0 = *(const bf16x8*)&H_sh[l16][ks * 32 + quad * 8];
    bf16x8 af1 = *(const bf16x8*)&H_sh[16 + l16][ks * 32 + quad * 8];
    const u16* wp = W2p + ((size_t)(k * 16 + ks) * 512 +
                           (nh * 256 + w * 64 + l16)) * 32 + quad * 8;
#pragma unroll
    for (int nt = 0; nt < 4; ++nt) {
      bf16x8 bf = *(const bf16x8*)(wp + (size_t)nt * 16 * 32);
      acc[0][nt] = __builtin_amdgcn_mfma_f32_16x16x32_bf16(af0, bf, acc[0][nt], 0, 0, 0);
      acc[1][nt] = __builtin_amdgcn_mfma_f32_16x16x32_bf16(af1, bf, acc[1][nt], 0, 0, 0);
    }
  }

  float vmask[2][4];
#pragma unroll
  for (int mt = 0; mt < 2; ++mt)
#pragma unroll
    for (int r = 0; r < 4; ++r)
      vmask[mt][r] = (ridx[mt * 16 + quad * 4 + r] >= 0) ? 1.f : 0.f;

#pragma unroll
  for (int nt = 0; nt < 4; ++nt) {
    int col = nh * 256 + w * 64 + nt * 16 + l16;
    float bias = b2[k * DH + col];
    float s = 0.f;
#pragma unroll
    for (int mt = 0; mt < 2; ++mt)
#pragma unroll
      for (int r = 0; r < 4; ++r)
        s += vmask[mt][r] * fmaxf(acc[mt][nt][r] + bias, 0.f);
    s += __shfl_xor(s, 16, 64);
    s += __shfl_xor(s, 32, 64);
    if (quad == 0) atomicAdd(&psum[k * DH + col], s);
  }
}

// fc: h = relu(pooled @ fcW + fcb). grid (KC, 2); 256 outputs per block.
__global__ __launch_bounds__(256) void fc_kernel(
    const float* __restrict__ psum, const int* __restrict__ cnt,
    const float* __restrict__ fcW, const float* __restrict__ fcb,
    float* __restrict__ hstore) {
  int k = blockIdx.x, half = blockIdx.y, tid = threadIdx.x;
  __shared__ float p_sh[DH];
  int c = cnt[k];
  float inv = (c > 0) ? 1.f / (float)c : 0.f;
  for (int d = tid; d < DH; d += 256) p_sh[d] = psum[k * DH + d] * inv;
  __syncthreads();
  int j = half * 256 + tid;
  float s0 = 0.f, s1 = 0.f, s2 = 0.f, s3 = 0.f;
  for (int d = 0; d < DH; d += 4) {
    s0 = fmaf(p_sh[d + 0], fcW[(d + 0) * DH + j], s0);
    s1 = fmaf(p_sh[d + 1], fcW[(d + 1) * DH + j], s1);
    s2 = fmaf(p_sh[d + 2], fcW[(d + 2) * DH + j], s2);
    s3 = fmaf(p_sh[d + 3], fcW[(d + 3) * DH + j], s3);
  }
  hstore[k * DH + j] = fmaxf((s0 + s1) + (s2 + s3) + fcb[j], 0.f);
}

// gated attention partial score. grid (KC, 2) x 128 thr; bc dropped
// (softmax is shift-invariant). Accumulates into zeroed sstore.
__global__ __launch_bounds__(128) void attn_kernel(
    const float* __restrict__ hstore, const float* __restrict__ Va,
    const float* __restrict__ ba, const float* __restrict__ Vb,
    const float* __restrict__ bb_, const float* __restrict__ Vc,
    float* __restrict__ sstore) {
  int k = blockIdx.x, half = blockIdx.y, tid = threadIdx.x;
  __shared__ float h_sh[DH];
  __shared__ float red[128];
  for (int d = tid; d < DH; d += 128) h_sh[d] = hstore[k * DH + d];
  __syncthreads();
  int j = half * 128 + tid;
  float sa0 = 0.f, sa1 = 0.f, sb0 = 0.f, sb1 = 0.f;
  for (int d = 0; d < DH; d += 2) {
    float h0 = h_sh[d], h1v = h_sh[d + 1];
    sa0 = fmaf(h0, Va[(d + 0) * DA + j], sa0);
    sa1 = fmaf(h1v, Va[(d + 1) * DA + j], sa1);
    sb0 = fmaf(h0, Vb[(d + 0) * DA + j], sb0);
    sb1 = fmaf(h1v, Vb[(d + 1) * DA + j], sb1);
  }
  float a = tanhf(sa0 + sa1 + ba[j]);
  float b = 1.f / (1.f + expf(-(sb0 + sb1 + bb_[j])));
  red[tid] = a * b * Vc[j];
  __syncthreads();
  for (int s = 64; s > 0; s >>= 1) {
    if (tid < s) red[tid] += red[tid + s];
    __syncthreads();
  }
  if (tid == 0) atomicAdd(&sstore[k], red[0]);
}

// softmax over K -> h_path -> rho -> classifier -> hazards/S/Y_hat. 1 block.
__global__ __launch_bounds__(256) void tail_kernel(
    const float* __restrict__ hstore, const float* __restrict__ sstore,
    const float* __restrict__ rhoW, const float* __restrict__ rhob,
    const float* __restrict__ clsW, const float* __restrict__ clsb,
    float* __restrict__ out) {
  int tid = threadIdx.x;
  __shared__ float hp_sh[DH];
  __shared__ float h2_sh[DA];
  __shared__ float lg[NCLS];

  float sv[KC];
  float m = -1e30f;
#pragma unroll
  for (int k = 0; k < KC; ++k) {
    sv[k] = sstore[k];
    m = fmaxf(m, sv[k]);
  }
  float Z = 0.f;
#pragma unroll
  for (int k = 0; k < KC; ++k) {
    sv[k] = expf(sv[k] - m);
    Z += sv[k];
  }
  float invZ = 1.f / Z;

#pragma unroll
  for (int jj = 0; jj < 2; ++jj) {
    int d = tid + jj * 256;
    float s = 0.f;
#pragma unroll
    for (int k = 0; k < KC; ++k) s = fmaf(sv[k] * invZ, hstore[k * DH + d], s);
    hp_sh[d] = s;
  }
  __syncthreads();

  if (tid < DA) {
    float s0 = 0.f, s1 = 0.f, s2 = 0.f, s3 = 0.f;
    for (int d = 0; d < DH; d += 4) {
      s0 = fmaf(hp_sh[d + 0], rhoW[(d + 0) * DA + tid], s0);
      s1 = fmaf(hp_sh[d + 1], rhoW[(d + 1) * DA + tid], s1);
      s2 = fmaf(hp_sh[d + 2], rhoW[(d + 2) * DA + tid], s2);
      s3 = fmaf(hp_sh[d + 3], rhoW[(d + 3) * DA + tid], s3);
    }
    h2_sh[tid] = fmaxf((s0 + s1) + (s2 + s3) + rhob[tid], 0.f);
  }
  __syncthreads();

  if (tid < NCLS) {
    float s = clsb[tid];
    for (int d = 0; d < DA; ++d) s = fmaf(h2_sh[d], clsW[d * NCLS + tid], s);
    lg[tid] = s;
  }
  __syncthreads();

  if (tid == 0) {
    float hz[NCLS];
    int best = 0;
#pragma unroll
    for (int c = 0; c < NCLS; ++c) {
      hz[c] = 1.f / (1.f + expf(-lg[c]));
      if (lg[c] > lg[best]) best = c;
    }
    float S = 1.f;
#pragma unroll
    for (int c = 0; c < NCLS; ++c) out[c] = hz[c];
#pragma unroll
    for (int c = 0; c < NCLS; ++c) {
      S *= (1.f - hz[c]);
      out[NCLS + c] = S;
    }
    out[2 * NCLS] = (float)best;
  }
}

extern "C" void kernel_launch(void* const* d_in, const int* in_sizes, int n_in,
                              void* d_out, int out_size, void* d_ws,
                              size_t ws_size, hipStream_t stream) {
  const float* x    = (const float*)d_in[0];
  const int*   cid  = (const int*)d_in[1];
  const float* W1   = (const float*)d_in[2];
  const float* b1   = (const float*)d_in[3];
  const float* W2   = (const float*)d_in[4];
  const float* b2   = (const float*)d_in[5];
  const float* fcW  = (const float*)d_in[6];
  const float* fcb  = (const float*)d_in[7];
  const float* Va   = (const float*)d_in[8];
  const float* ba   = (const float*)d_in[9];
  const float* Vb   = (const float*)d_in[10];
  const float* bb_  = (const float*)d_in[11];
  const float* Vc   = (const float*)d_in[12];
  const float* rhoW = (const float*)d_in[14];
  const float* rhob = (const float*)d_in[15];
  const float* clsW = (const float*)d_in[16];
  const float* clsb = (const float*)d_in[17];
  float* out = (float*)d_out;

  char* ws = (char*)d_ws;
  int*   cnt     = (int*)(ws + OFF_CNT);
  int*   idxlist = (int*)(ws + OFF_IDX);
  float* psum    = (float*)(ws + OFF_PSUM);
  float* hstore  = (float*)(ws + OFF_H);
  float* sstore  = (float*)(ws + OFF_S);
  u16*   W1p     = (u16*)(ws + OFF_W1P);
  u16*   W2p     = (u16*)(ws + OFF_W2P);
  u16*   xb      = (u16*)(ws + OFF_XB);
  u16*   h1      = (u16*)(ws + OFF_H1);

  (void)hipMemsetAsync(cnt, 0, 64, stream);
  prep_kernel<<<NB_PREP, 256, 0, stream>>>(cid, cnt, idxlist, W1, W2, W1p, W2p,
                                           x, xb, psum, sstore);
  phi1_kernel<<<dim3(64, KC, 2), 256, 0, stream>>>(xb, W1p, b1, cnt, idxlist, h1);
  phi2_kernel<<<dim3(64, KC, 2), 256, 0, stream>>>(h1, W2p, b2, cnt, idxlist, psum);
  fc_kernel<<<dim3(KC, 2), 256, 0, stream>>>(psum, cnt, fcW, fcb, hstore);
  attn_kernel<<<dim3(KC, 2), 128, 0, stream>>>(hstore, Va, ba, Vb, bb_, Vc, sstore);
  tail_kernel<<<1, 256, 0, stream>>>(hstore, sstore, rhoW, rhob, clsW, clsb, out);
}

// Round 5
// 262.371 us; speedup vs baseline: 2.2416x; 1.0301x over previous
//
#include <hip/hip_runtime.h>
#include <math.h>

// Problem constants (from reference)
#define NPATCH 8192
#define KC     10
#define DIN    1024
#define DH     512
#define DA     256
#define NCLS   4

#define TM  32    // patches per phi block
#define LDA 520   // padded LDS row stride (u16): 1040 B -> b128 frag reads spread banks

typedef unsigned short u16;
typedef short bf16x8 __attribute__((ext_vector_type(8)));   // 8 bf16 = 4 VGPRs
typedef float f32x4  __attribute__((ext_vector_type(4)));

// Workspace layout (bytes)
#define OFF_CNT   0                  // int[KC] (64B)
#define OFF_IDX   64                 // int[KC*NPATCH]
#define OFF_PSUM  327744             // float[KC*DH]
#define OFF_H     348224             // float[KC*DH]
#define OFF_S     368704             // float[KC] (64B)
#define OFF_W1P   368768             // u16[KC*DIN*DH]
#define OFF_W2P   10854528           // u16[KC*DH*DH]
#define OFF_XB    16097408           // u16[NPATCH*DIN]
#define OFF_H1    32874624           // u16[NPATCH*DH]
// total ~41.3 MB

__device__ __forceinline__ u16 f2bf(float f) {
  union { float f; unsigned u; } v; v.f = f;
  unsigned r = (v.u + 0x7fffu + ((v.u >> 16) & 1u)) >> 16;  // RNE
  return (u16)r;
}

struct __align__(8) U16x4 { u16 x, y, z, w; };

// Async global->LDS DMA, 16B/lane; LDS dest = wave-uniform base + lane*16.
__device__ __forceinline__ void async16(const void* gp, void* lp) {
  __builtin_amdgcn_global_load_lds(
      (const __attribute__((address_space(1))) void*)gp,
      (__attribute__((address_space(3))) void*)lp, 16, 0, 0);
}

#define W1_TILES (KC * (DIN / 32) * (DH / 32))  // 5120
#define W2_TILES (KC * (DH / 32) * (DH / 32))   // 2560
#define NB_BUCKET 32
#define NB_XB     2048
#define NB_PREP   (NB_BUCKET + W1_TILES + W2_TILES + NB_XB)  // 9760

// Fused prep: bucket + zero psum/sstore (blocks 0..31), pack W1/W2 -> bf16
// MFMA-B panels [k][kb][n][ki], pack x -> bf16 row-major.
__global__ __launch_bounds__(256) void prep_kernel(
    const int* __restrict__ cid, int* __restrict__ cnt,
    int* __restrict__ idxlist, const float* __restrict__ W1,
    const float* __restrict__ W2, u16* __restrict__ W1p,
    u16* __restrict__ W2p, const float* __restrict__ x,
    u16* __restrict__ xb, float* __restrict__ psum,
    float* __restrict__ sstore) {
  int b = blockIdx.x, t = threadIdx.x;
  if (b < NB_BUCKET) {
    int g = b * 256 + t;
    if (g < KC * DH) psum[g] = 0.f;
    if (g < KC) sstore[g] = 0.f;
    __shared__ int lcnt[KC], lbase[KC];
    if (t < KC) lcnt[t] = 0;
    __syncthreads();
    int n = b * 256 + t;                 // NPATCH == 32*256
    int k = cid[n];
    int myoff = atomicAdd(&lcnt[k], 1);
    __syncthreads();
    if (t < KC) lbase[t] = atomicAdd(&cnt[t], lcnt[t]);
    __syncthreads();
    idxlist[k * NPATCH + lbase[k] + myoff] = n;
  } else if (b < NB_BUCKET + W1_TILES + W2_TILES) {
    __shared__ u16 tile[32][33];
    int bb = b - NB_BUCKET;
    const float* src;
    u16* dst;
    if (bb < W1_TILES) {
      int k = bb / 512, rem = bb % 512;
      int kb = rem / 16, n0 = (rem % 16) * 32;
      src = W1 + (size_t)k * DIN * DH + (size_t)kb * 32 * DH + n0;
      dst = W1p + (((size_t)(k * 32 + kb) * 512 + n0) * 32);
    } else {
      int b2 = bb - W1_TILES;
      int k = b2 / 256, rem = b2 % 256;
      int kb = rem / 16, n0 = (rem % 16) * 32;
      src = W2 + (size_t)k * DH * DH + (size_t)kb * 32 * DH + n0;
      dst = W2p + (((size_t)(k * 16 + kb) * 512 + n0) * 32);
    }
    // vectorized: 256 thr x float4 = one 32x32 tile read in one wave-round
    {
      int ki = t >> 3, n4 = (t & 7) * 4;
      float4 v = *(const float4*)&src[(size_t)ki * DH + n4];
      tile[ki][n4 + 0] = f2bf(v.x);
      tile[ki][n4 + 1] = f2bf(v.y);
      tile[ki][n4 + 2] = f2bf(v.z);
      tile[ki][n4 + 3] = f2bf(v.w);
    }
    __syncthreads();
    {
      int n = t >> 3, ki = (t & 7) * 4;
      U16x4 o = {tile[ki + 0][n], tile[ki + 1][n], tile[ki + 2][n],
                 tile[ki + 3][n]};
      *(U16x4*)&dst[(size_t)n * 32 + ki] = o;
    }
  } else {
    int cb = b - (NB_BUCKET + W1_TILES + W2_TILES);
    size_t basei = (size_t)cb * 4096;
#pragma unroll
    for (int i = 0; i < 4; ++i) {
      size_t off = basei + (size_t)i * 1024 + (size_t)t * 4;
      float4 v = *(const float4*)(x + off);
      U16x4 o = {f2bf(v.x), f2bf(v.y), f2bf(v.z), f2bf(v.w)};
      *(U16x4*)(xb + off) = o;
    }
  }
}

// Layer 1: h1 = relu(x @ W1[k] + b1[k]) for this cluster's patches, bf16 out.
// grid (64, KC, 2). 4 waves; wave w owns 64 cols of its 256-col half.
// K-loop: fully unrolled, double-buffered 2-ks B-fragment prefetch.
__global__ __launch_bounds__(256) void phi1_kernel(
    const u16* __restrict__ xb, const u16* __restrict__ W1p,
    const float* __restrict__ b1, const int* __restrict__ cnt,
    const int* __restrict__ idxlist, u16* __restrict__ h1) {
  const int k = blockIdx.y;
  const int base = blockIdx.x * TM;
  const int nh = blockIdx.z;
  const int cntk = cnt[k];
  if (base >= cntk) return;

  const int tid = threadIdx.x;
  const int w = tid >> 6, lane = tid & 63;
  const int quad = lane >> 4, l16 = lane & 15;

  __shared__ __align__(16) u16 A_sh[TM][LDA];  // 33.3 KB
  __shared__ int ridx[TM];
  if (tid < TM) {
    int r = base + tid;
    ridx[tid] = (r < cntk) ? idxlist[k * NPATCH + r] : -1;
  }
  __syncthreads();

  const f32x4 zero4 = {0.f, 0.f, 0.f, 0.f};
  f32x4 acc[2][4];
#pragma unroll
  for (int mt = 0; mt < 2; ++mt)
#pragma unroll
    for (int nt = 0; nt < 4; ++nt) acc[mt][nt] = zero4;

  for (int kh = 0; kh < 2; ++kh) {
    if (kh) __syncthreads();
    // stage 8 rows per wave via DMA (1 KB row-half each), zero-fill padded
    for (int rr = 0; rr < 8; ++rr) {
      int r = w * 8 + rr;
      int src = ridx[r];
      if (src >= 0) {
        async16(xb + (size_t)src * DIN + kh * 512 + lane * 8, &A_sh[r][0]);
      } else {
        bf16x8 z = {0, 0, 0, 0, 0, 0, 0, 0};
        *(bf16x8*)&A_sh[r][lane * 8] = z;
      }
    }
    __syncthreads();

    // B base for this wave: col = nh*256 + w*64 + l16; ks stride 16384 u16,
    // nt stride 512 u16.
    const u16* wb = W1p + ((size_t)(k * 32 + kh * 16) * 512 +
                           (nh * 256 + w * 64 + l16)) * 32 + quad * 8;
    bf16x8 B[2][8];
#pragma unroll
    for (int s = 0; s < 2; ++s)
#pragma unroll
      for (int nt = 0; nt < 4; ++nt)
        B[0][s * 4 + nt] = *(const bf16x8*)(wb + (size_t)s * 16384 + nt * 512);
#pragma unroll
    for (int g = 0; g < 8; ++g) {
      const int cur = g & 1, nxt = cur ^ 1;
      if (g < 7) {
#pragma unroll
        for (int s = 0; s < 2; ++s)
#pragma unroll
          for (int nt = 0; nt < 4; ++nt)
            B[nxt][s * 4 + nt] = *(const bf16x8*)(
                wb + (size_t)(g * 2 + 2 + s) * 16384 + nt * 512);
      }
#pragma unroll
      for (int s = 0; s < 2; ++s) {
        const int ks = g * 2 + s;
        bf16x8 af0 = *(const bf16x8*)&A_sh[l16][ks * 32 + quad * 8];
        bf16x8 af1 = *(const bf16x8*)&A_sh[16 + l16][ks * 32 + quad * 8];
#pragma unroll
        for (int nt = 0; nt < 4; ++nt) {
          acc[0][nt] = __builtin_amdgcn_mfma_f32_16x16x32_bf16(
              af0, B[cur][s * 4 + nt], acc[0][nt], 0, 0, 0);
          acc[1][nt] = __builtin_amdgcn_mfma_f32_16x16x32_bf16(
              af1, B[cur][s * 4 + nt], acc[1][nt], 0, 0, 0);
        }
      }
    }
  }

  // epilogue: bias+relu -> bf16 via LDS transpose -> coalesced h1 writes
  __syncthreads();
#pragma unroll
  for (int mt = 0; mt < 2; ++mt)
#pragma unroll
    for (int nt = 0; nt < 4; ++nt) {
      int c = w * 64 + nt * 16 + l16;
      float bias = b1[k * DH + nh * 256 + c];
#pragma unroll
      for (int r = 0; r < 4; ++r) {
        int row = mt * 16 + quad * 4 + r;
        A_sh[row][c] = f2bf(fmaxf(acc[mt][nt][r] + bias, 0.f));
      }
    }
  __syncthreads();
  {
    int row = tid >> 3, part = tid & 7;
    int n = ridx[row];
    if (n >= 0) {
      u16* dst = h1 + (size_t)n * DH + nh * 256 + part * 32;
#pragma unroll
      for (int j = 0; j < 4; ++j)
        *(bf16x8*)(dst + j * 8) = *(const bf16x8*)&A_sh[row][part * 32 + j * 8];
    }
  }
}

// Layer 2 + masked mean-pool numerator: psum[k] += relu(h1 @ W2[k] + b2[k]).
__global__ __launch_bounds__(256) void phi2_kernel(
    const u16* __restrict__ h1, const u16* __restrict__ W2p,
    const float* __restrict__ b2, const int* __restrict__ cnt,
    const int* __restrict__ idxlist, float* __restrict__ psum) {
  const int k = blockIdx.y;
  const int base = blockIdx.x * TM;
  const int nh = blockIdx.z;
  const int cntk = cnt[k];
  if (base >= cntk) return;

  const int tid = threadIdx.x;
  const int w = tid >> 6, lane = tid & 63;
  const int quad = lane >> 4, l16 = lane & 15;

  __shared__ __align__(16) u16 H_sh[TM][LDA];
  __shared__ int ridx[TM];
  if (tid < TM) {
    int r = base + tid;
    ridx[tid] = (r < cntk) ? idxlist[k * NPATCH + r] : -1;
  }
  __syncthreads();

  for (int rr = 0; rr < 8; ++rr) {
    int r = w * 8 + rr;
    int src = ridx[r];
    if (src >= 0) {
      async16(h1 + (size_t)src * DH + lane * 8, &H_sh[r][0]);
    } else {
      bf16x8 z = {0, 0, 0, 0, 0, 0, 0, 0};
      *(bf16x8*)&H_sh[r][lane * 8] = z;
    }
  }
  __syncthreads();

  const f32x4 zero4 = {0.f, 0.f, 0.f, 0.f};
  f32x4 acc[2][4];
#pragma unroll
  for (int mt = 0; mt < 2; ++mt)
#pragma unroll
    for (int nt = 0; nt < 4; ++nt) acc[mt][nt] = zero4;

  const u16* wb = W2p + ((size_t)(k * 16) * 512 +
                         (nh * 256 + w * 64 + l16)) * 32 + quad * 8;
  bf16x8 B[2][8];
#pragma unroll
  for (int s = 0; s < 2; ++s)
#pragma unroll
    for (int nt = 0; nt < 4; ++nt)
      B[0][s * 4 + nt] = *(const bf16x8*)(wb + (size_t)s * 16384 + nt * 512);
#pragma unroll
  for (int g = 0; g < 8; ++g) {
    const int cur = g & 1, nxt = cur ^ 1;
    if (g < 7) {
#pragma unroll
      for (int s = 0; s < 2; ++s)
#pragma unroll
        for (int nt = 0; nt < 4; ++nt)
          B[nxt][s * 4 + nt] = *(const bf16x8*)(
              wb + (size_t)(g * 2 + 2 + s) * 16384 + nt * 512);
    }
#pragma unroll
    for (int s = 0; s < 2; ++s) {
      const int ks = g * 2 + s;
      bf16x8 af0 = *(const bf16x8*)&H_sh[l16][ks * 32 + quad * 8];
      bf16x8 af1 = *(const bf16x8*)&H_sh[16 + l16][ks * 32 + quad * 8];
#pragma unroll
      for (int nt = 0; nt < 4; ++nt) {
        acc[0][nt] = __builtin_amdgcn_mfma_f32_16x16x32_bf16(
            af0, B[cur][s * 4 + nt], acc[0][nt], 0, 0, 0);
        acc[1][nt] = __builtin_amdgcn_mfma_f32_16x16x32_bf16(
            af1, B[cur][s * 4 + nt], acc[1][nt], 0, 0, 0);
      }
    }
  }

  float vmask[2][4];
#pragma unroll
  for (int mt = 0; mt < 2; ++mt)
#pragma unroll
    for (int r = 0; r < 4; ++r)
      vmask[mt][r] = (ridx[mt * 16 + quad * 4 + r] >= 0) ? 1.f : 0.f;

#pragma unroll
  for (int nt = 0; nt < 4; ++nt) {
    int col = nh * 256 + w * 64 + nt * 16 + l16;
    float bias = b2[k * DH + col];
    float s = 0.f;
#pragma unroll
    for (int mt = 0; mt < 2; ++mt)
#pragma unroll
      for (int r = 0; r < 4; ++r)
        s += vmask[mt][r] * fmaxf(acc[mt][nt][r] + bias, 0.f);
    s += __shfl_xor(s, 16, 64);
    s += __shfl_xor(s, 32, 64);
    if (quad == 0) atomicAdd(&psum[k * DH + col], s);
  }
}

// fc: h = relu(pooled @ fcW + fcb). grid (KC, 2); 256 outputs per block.
__global__ __launch_bounds__(256) void fc_kernel(
    const float* __restrict__ psum, const int* __restrict__ cnt,
    const float* __restrict__ fcW, const float* __restrict__ fcb,
    float* __restrict__ hstore) {
  int k = blockIdx.x, half = blockIdx.y, tid = threadIdx.x;
  __shared__ float p_sh[DH];
  int c = cnt[k];
  float inv = (c > 0) ? 1.f / (float)c : 0.f;
  for (int d = tid; d < DH; d += 256) p_sh[d] = psum[k * DH + d] * inv;
  __syncthreads();
  int j = half * 256 + tid;
  float s[8] = {0.f, 0.f, 0.f, 0.f, 0.f, 0.f, 0.f, 0.f};
  for (int d = 0; d < DH; d += 8) {
#pragma unroll
    for (int u = 0; u < 8; ++u)
      s[u] = fmaf(p_sh[d + u], fcW[(size_t)(d + u) * DH + j], s[u]);
  }
  float t0 = (s[0] + s[1]) + (s[2] + s[3]), t1 = (s[4] + s[5]) + (s[6] + s[7]);
  hstore[k * DH + j] = fmaxf(t0 + t1 + fcb[j], 0.f);
}

// gated attention partial score. grid (KC, 2) x 128 thr; bc dropped
// (softmax is shift-invariant). Accumulates into zeroed sstore.
__global__ __launch_bounds__(128) void attn_kernel(
    const float* __restrict__ hstore, const float* __restrict__ Va,
    const float* __restrict__ ba, const float* __restrict__ Vb,
    const float* __restrict__ bb_, const float* __restrict__ Vc,
    float* __restrict__ sstore) {
  int k = blockIdx.x, half = blockIdx.y, tid = threadIdx.x;
  __shared__ float h_sh[DH];
  __shared__ float red[128];
  for (int d = tid; d < DH; d += 128) h_sh[d] = hstore[k * DH + d];
  __syncthreads();
  int j = half * 128 + tid;
  float sa[4] = {0.f, 0.f, 0.f, 0.f}, sb[4] = {0.f, 0.f, 0.f, 0.f};
  for (int d = 0; d < DH; d += 4) {
#pragma unroll
    for (int u = 0; u < 4; ++u) {
      float h = h_sh[d + u];
      sa[u] = fmaf(h, Va[(size_t)(d + u) * DA + j], sa[u]);
      sb[u] = fmaf(h, Vb[(size_t)(d + u) * DA + j], sb[u]);
    }
  }
  float a = tanhf((sa[0] + sa[1]) + (sa[2] + sa[3]) + ba[j]);
  float b = 1.f / (1.f + expf(-((sb[0] + sb[1]) + (sb[2] + sb[3]) + bb_[j])));
  red[tid] = a * b * Vc[j];
  __syncthreads();
  for (int s = 64; s > 0; s >>= 1) {
    if (tid < s) red[tid] += red[tid + s];
    __syncthreads();
  }
  if (tid == 0) atomicAdd(&sstore[k], red[0]);
}

// softmax over K -> h_path -> rho -> classifier -> hazards/S/Y_hat. 1 block.
__global__ __launch_bounds__(256) void tail_kernel(
    const float* __restrict__ hstore, const float* __restrict__ sstore,
    const float* __restrict__ rhoW, const float* __restrict__ rhob,
    const float* __restrict__ clsW, const float* __restrict__ clsb,
    float* __restrict__ out) {
  int tid = threadIdx.x;
  __shared__ float hp_sh[DH];
  __shared__ float h2_sh[DA];
  __shared__ float lg[NCLS];

  float sv[KC];
  float m = -1e30f;
#pragma unroll
  for (int k = 0; k < KC; ++k) {
    sv[k] = sstore[k];
    m = fmaxf(m, sv[k]);
  }
  float Z = 0.f;
#pragma unroll
  for (int k = 0; k < KC; ++k) {
    sv[k] = expf(sv[k] - m);
    Z += sv[k];
  }
  float invZ = 1.f / Z;

#pragma unroll
  for (int jj = 0; jj < 2; ++jj) {
    int d = tid + jj * 256;
    float s = 0.f;
#pragma unroll
    for (int k = 0; k < KC; ++k) s = fmaf(sv[k] * invZ, hstore[k * DH + d], s);
    hp_sh[d] = s;
  }
  __syncthreads();

  if (tid < DA) {
    float s[8] = {0.f, 0.f, 0.f, 0.f, 0.f, 0.f, 0.f, 0.f};
    for (int d = 0; d < DH; d += 8) {
#pragma unroll
      for (int u = 0; u < 8; ++u)
        s[u] = fmaf(hp_sh[d + u], rhoW[(size_t)(d + u) * DA + tid], s[u]);
    }
    float t0 = (s[0] + s[1]) + (s[2] + s[3]),
          t1 = (s[4] + s[5]) + (s[6] + s[7]);
    h2_sh[tid] = fmaxf(t0 + t1 + rhob[tid], 0.f);
  }
  __syncthreads();

  if (tid < NCLS) {
    float s[4] = {0.f, 0.f, 0.f, 0.f};
    for (int d = 0; d < DA; d += 4) {
#pragma unroll
      for (int u = 0; u < 4; ++u)
        s[u] = fmaf(h2_sh[d + u], clsW[(size_t)(d + u) * NCLS + tid], s[u]);
    }
    lg[tid] = (s[0] + s[1]) + (s[2] + s[3]) + clsb[tid];
  }
  __syncthreads();

  if (tid == 0) {
    float hz[NCLS];
    int best = 0;
#pragma unroll
    for (int c = 0; c < NCLS; ++c) {
      hz[c] = 1.f / (1.f + expf(-lg[c]));
      if (lg[c] > lg[best]) best = c;
    }
    float S = 1.f;
#pragma unroll
    for (int c = 0; c < NCLS; ++c) out[c] = hz[c];
#pragma unroll
    for (int c = 0; c < NCLS; ++c) {
      S *= (1.f - hz[c]);
      out[NCLS + c] = S;
    }
    out[2 * NCLS] = (float)best;
  }
}

extern "C" void kernel_launch(void* const* d_in, const int* in_sizes, int n_in,
                              void* d_out, int out_size, void* d_ws,
                              size_t ws_size, hipStream_t stream) {
  const float* x    = (const float*)d_in[0];
  const int*   cid  = (const int*)d_in[1];
  const float* W1   = (const float*)d_in[2];
  const float* b1   = (const float*)d_in[3];
  const float* W2   = (const float*)d_in[4];
  const float* b2   = (const float*)d_in[5];
  const float* fcW  = (const float*)d_in[6];
  const float* fcb  = (const float*)d_in[7];
  const float* Va   = (const float*)d_in[8];
  const float* ba   = (const float*)d_in[9];
  const float* Vb   = (const float*)d_in[10];
  const float* bb_  = (const float*)d_in[11];
  const float* Vc   = (const float*)d_in[12];
  const float* rhoW = (const float*)d_in[14];
  const float* rhob = (const float*)d_in[15];
  const float* clsW = (const float*)d_in[16];
  const float* clsb = (const float*)d_in[17];
  float* out = (float*)d_out;

  char* ws = (char*)d_ws;
  int*   cnt     = (int*)(ws + OFF_CNT);
  int*   idxlist = (int*)(ws + OFF_IDX);
  float* psum    = (float*)(ws + OFF_PSUM);
  float* hstore  = (float*)(ws + OFF_H);
  float* sstore  = (float*)(ws + OFF_S);
  u16*   W1p     = (u16*)(ws + OFF_W1P);
  u16*   W2p     = (u16*)(ws + OFF_W2P);
  u16*   xb      = (u16*)(ws + OFF_XB);
  u16*   h1      = (u16*)(ws + OFF_H1);

  (void)hipMemsetAsync(cnt, 0, 64, stream);
  prep_kernel<<<NB_PREP, 256, 0, stream>>>(cid, cnt, idxlist, W1, W2, W1p, W2p,
                                           x, xb, psum, sstore);
  phi1_kernel<<<dim3(64, KC, 2), 256, 0, stream>>>(xb, W1p, b1, cnt, idxlist, h1);
  phi2_kernel<<<dim3(64, KC, 2), 256, 0, stream>>>(h1, W2p, b2, cnt, idxlist, psum);
  fc_kernel<<<dim3(KC, 2), 256, 0, stream>>>(psum, cnt, fcW, fcb, hstore);
  attn_kernel<<<dim3(KC, 2), 128, 0, stream>>>(hstore, Va, ba, Vb, bb_, Vc, sstore);
  tail_kernel<<<1, 256, 0, stream>>>(hstore, sstore, rhoW, rhob, clsW, clsb, out);
}